// Round 4
// baseline (362.960 us; speedup 1.0000x reference)
//
#include <hip/hip_runtime.h>
#include <math.h>

#define H    128
#define TT   128
#define CH   8            // steps per chunk/flag
#define NCH  (TT / CH)    // 16
#define RD   4            // partials ring depth (chunks)

// ws float offsets
#define OFF_H1V   0                 // [b][t][256]           : 262144 floats
#define OFF_P1    262144            // [b][RD][CH][512]      : 131072 floats
#define OFF_P2    393216            // [b][RD][CH][512]      : 131072 floats
#define OFF_CNT   524288            // int counters (1024 reserved)
#define OFF_GBUF  525312            // [b][t]                : 1024 floats

__device__ __forceinline__ float sigf(float x)       { return 1.0f / (1.0f + __expf(-x)); }
__device__ __forceinline__ float tanhf_fast(float x) { return 1.0f - 2.0f / (1.0f + __expf(2.0f * x)); }

// Load one float4 of the weight row and pin its scalars in VGPRs via opaque
// asm — the post-asm values cannot be rematerialized as L2 loads.
#define DECLW(i) \
    float4 t##i = wp[i]; \
    float w##i##0 = t##i.x, w##i##1 = t##i.y, w##i##2 = t##i.z, w##i##3 = t##i.w; \
    asm volatile("" : "+v"(w##i##0), "+v"(w##i##1), "+v"(w##i##2), "+v"(w##i##3));

#define LOADW \
    DECLW(0)  DECLW(1)  DECLW(2)  DECLW(3)  DECLW(4)  DECLW(5)  DECLW(6)  DECLW(7)  \
    DECLW(8)  DECLW(9)  DECLW(10) DECLW(11) DECLW(12) DECLW(13) DECLW(14) DECLW(15) \
    DECLW(16) DECLW(17) DECLW(18) DECLW(19) DECLW(20) DECLW(21) DECLW(22) DECLW(23) \
    DECLW(24) DECLW(25) DECLW(26) DECLW(27) DECLW(28) DECLW(29) DECLW(30) DECLW(31)

#define FMA4(i, hv, s) { const float4 _h4 = (hv); \
    s = fmaf(w##i##0, _h4.x, s); s = fmaf(w##i##1, _h4.y, s); \
    s = fmaf(w##i##2, _h4.z, s); s = fmaf(w##i##3, _h4.w, s); }

// full 128-dot against LDS float4 array, 4 round-robin accumulators
#define DOT_ALL(HB, s0, s1, s2, s3) \
    FMA4(0,(HB)[0],s0)   FMA4(1,(HB)[1],s1)   FMA4(2,(HB)[2],s2)   FMA4(3,(HB)[3],s3)   \
    FMA4(4,(HB)[4],s0)   FMA4(5,(HB)[5],s1)   FMA4(6,(HB)[6],s2)   FMA4(7,(HB)[7],s3)   \
    FMA4(8,(HB)[8],s0)   FMA4(9,(HB)[9],s1)   FMA4(10,(HB)[10],s2) FMA4(11,(HB)[11],s3) \
    FMA4(12,(HB)[12],s0) FMA4(13,(HB)[13],s1) FMA4(14,(HB)[14],s2) FMA4(15,(HB)[15],s3) \
    FMA4(16,(HB)[16],s0) FMA4(17,(HB)[17],s1) FMA4(18,(HB)[18],s2) FMA4(19,(HB)[19],s3) \
    FMA4(20,(HB)[20],s0) FMA4(21,(HB)[21],s1) FMA4(22,(HB)[22],s2) FMA4(23,(HB)[23],s3) \
    FMA4(24,(HB)[24],s0) FMA4(25,(HB)[25],s1) FMA4(26,(HB)[26],s2) FMA4(27,(HB)[27],s3) \
    FMA4(28,(HB)[28],s0) FMA4(29,(HB)[29],s1) FMA4(30,(HB)[30],s2) FMA4(31,(HB)[31],s3)

#define WAITGE(ptr, val) \
    while (__hip_atomic_load(ptr, __ATOMIC_ACQUIRE, __HIP_MEMORY_SCOPE_AGENT) < (val)) \
        __builtin_amdgcn_s_sleep(1);

// ---------------------------------------------------------------------------
// 4-stage per-batch CU pipeline (32 blocks):
//   role 0 = A : layer-1 recurrence (w_hh0)        -> h1[t], v[t]
//   role 1 = B1: w_ih1 @ h1 (stateless, chunked)   -> part1
//   role 2 = B2: w_ih1 @ v  (stateless, chunked)   -> part2
//   role 3 = C : w_hh1 @ h2 + elementwise + output -> gbuf
// Each stage pins its full 512x128 weight matrix in registers (128 VGPR/thr).
// ---------------------------------------------------------------------------
__global__ __launch_bounds__(512, 1)
void lstm4_kernel(const float* __restrict__ x,
                  const float* __restrict__ w_ih0,
                  const float* __restrict__ w_hh0,
                  const float* __restrict__ b_ih0,
                  const float* __restrict__ b_hh0,
                  const float* __restrict__ w_ih1,
                  const float* __restrict__ w_hh1,
                  const float* __restrict__ b_ih1,
                  const float* __restrict__ b_hh1,
                  const float* __restrict__ w_out,
                  float* __restrict__ ws) {
    const int role = blockIdx.x >> 3;
    const int b    = blockIdx.x & 7;
    const int r    = threadIdx.x;

    int* cntA  = (int*)ws + OFF_CNT       + b * 16;
    int* cntB1 = (int*)ws + OFF_CNT + 128 + b * 16;
    int* cntB2 = (int*)ws + OFF_CNT + 256 + b * 16;
    int* cntC  = (int*)ws + OFF_CNT + 384 + b * 16;
    float* h1v = ws + OFF_H1V + b * TT * 256;

    __shared__ float4 hs4[32];           // state (A: h1, C: h2)
    __shared__ float  u_s[TT];
    __shared__ float  e1[512], e2[512];
    __shared__ float4 h1c4[CH * 32];     // B: staged chunk
    __shared__ float  red[2];
    float* hs = (float*)hs4;

    const bool is_g = (r >= 256) && (r < 384);   // wave-uniform gate blocks

    if (role == 0) {
        // ===================== Stage A: layer-1 recurrence =====================
        const float4* wp = reinterpret_cast<const float4*>(w_hh0 + r * H);
        LOADW
        const float wcol = w_ih0[r];
        const float bias = b_ih0[r] + b_hh0[r];
        {   // u[t] = trace(x[b,t]) computed by all 512 threads (4 partials per t)
            const float* xb = x + (size_t)(b * TT + (r & 127)) * 1024;
            const int p = r >> 7;
            float u = 0.f;
#pragma unroll
            for (int i = 0; i < 8; i++) u += xb[(p * 8 + i) * 33];
            e1[r] = u;
        }
        if (r < H) hs[r] = 0.f;
        __syncthreads();
        if (r < TT) u_s[r] = e1[r] + e1[r + 128] + e1[r + 256] + e1[r + 384];
        __syncthreads();

        float c1 = 0.f;
        for (int t = 0; t < TT; t++) {
            float s0 = fmaf(wcol, u_s[t], bias), s1 = 0.f, s2 = 0.f, s3 = 0.f;
            DOT_ALL(hs4, s0, s1, s2, s3)
            float z = (s0 + s1) + (s2 + s3);
            float a, d;
            if (is_g) { a = tanhf_fast(z); d = 1.f - a * a; }
            else      { a = sigf(z);       d = a * (1.f - a); }
            e1[r] = a; e2[r] = d * wcol;
            __syncthreads();
            if (r < H) {
                float i1 = e1[r], f1 = e1[r + 128], g1 = e1[r + 256], o1 = e1[r + 384];
                float di = e2[r], df = e2[r + 128], dg = e2[r + 256], dd = e2[r + 384];
                float dc = df * c1 + di * g1 + i1 * dg;
                c1 = f1 * c1 + i1 * g1;
                float th = tanhf_fast(c1);
                float hn = o1 * th;
                float vn = dd * th + o1 * (1.f - th * th) * dc;
                hs[r] = hn;
                h1v[t * 256 + r]       = hn;
                h1v[t * 256 + 128 + r] = vn;
            }
            __syncthreads();
            if ((t & (CH - 1)) == CH - 1) {
                __threadfence();
                if (r == 0)
                    __hip_atomic_store(cntA, t + 1, __ATOMIC_RELEASE, __HIP_MEMORY_SCOPE_AGENT);
            }
        }
    } else if (role == 1 || role == 2) {
        // ============ Stages B1/B2: w_ih1 @ (h1 | v), chunk-parallel ============
        const float4* wp = reinterpret_cast<const float4*>(w_ih1 + r * H);
        LOADW
        const int isB2 = (role == 2);
        int* myCnt   = isB2 ? cntB2 : cntB1;
        float* pbase = ws + (isB2 ? OFF_P2 : OFF_P1) + b * RD * CH * 512;
        const float* hsrc = h1v + (isB2 ? 128 : 0);
        for (int c = 0; c < NCH; c++) {
            if (r == 0) {
                WAITGE(cntA, (c + 1) * CH)
                if (c >= RD) WAITGE(cntC, (c - (RD - 1)) * CH)   // ring backpressure
            }
            __syncthreads();
            if (r < 256) {   // stage chunk: 8 steps x 128 floats
                int tl = r >> 5, k = r & 31;
                h1c4[r] = *reinterpret_cast<const float4*>(hsrc + (c * CH + tl) * 256 + k * 4);
            }
            __syncthreads();
            float* pslot = pbase + (c & (RD - 1)) * CH * 512;
#pragma unroll
            for (int tl = 0; tl < CH; tl++) {
                float s0 = 0.f, s1 = 0.f, s2 = 0.f, s3 = 0.f;
                DOT_ALL(h1c4 + tl * 32, s0, s1, s2, s3)
                pslot[tl * 512 + r] = (s0 + s1) + (s2 + s3);
            }
            __threadfence();
            __syncthreads();   // all threads' stores drained before flag
            if (r == 0)
                __hip_atomic_store(myCnt, (c + 1) * CH, __ATOMIC_RELEASE, __HIP_MEMORY_SCOPE_AGENT);
        }
    } else {
        // ========= Stage C: w_hh1 @ h2 + layer-2 elementwise + output =========
        const float4* wp = reinterpret_cast<const float4*>(w_hh1 + r * H);
        LOADW
        const float bias = b_ih1[r] + b_hh1[r];
        const float wout = (r < H) ? w_out[r] : 0.f;
        if (r < H) hs[r] = 0.f;
        __syncthreads();
        float c2 = 0.f;
        float* gb = ws + OFF_GBUF + b * TT;
        const float* p1 = ws + OFF_P1 + b * RD * CH * 512;
        const float* p2 = ws + OFF_P2 + b * RD * CH * 512;
        for (int c = 0; c < NCH; c++) {
            if (r == 0) { WAITGE(cntB1, (c + 1) * CH) WAITGE(cntB2, (c + 1) * CH) }
            __syncthreads();
            const float* s1p = p1 + (c & (RD - 1)) * CH * 512;
            const float* s2p = p2 + (c & (RD - 1)) * CH * 512;
            float z2p[CH], adp[CH];   // prefetch whole chunk's partials (hide L2 lat)
#pragma unroll
            for (int tl = 0; tl < CH; tl++) {
                z2p[tl] = s1p[tl * 512 + r];
                adp[tl] = s2p[tl * 512 + r];
            }
            for (int tl = 0; tl < CH; tl++) {
                float s0 = bias + z2p[tl], s1 = 0.f, s2 = 0.f, s3 = 0.f;
                DOT_ALL(hs4, s0, s1, s2, s3)
                float z = (s0 + s1) + (s2 + s3);
                float a, d;
                if (is_g) { a = tanhf_fast(z); d = 1.f - a * a; }
                else      { a = sigf(z);       d = a * (1.f - a); }
                e1[r] = a; e2[r] = d * adp[tl];
                __syncthreads();
                if (r < H) {
                    float i2 = e1[r], f2 = e1[r + 128], g2 = e1[r + 256], o2 = e1[r + 384];
                    float di = e2[r], df = e2[r + 128], dg = e2[r + 256], dd = e2[r + 384];
                    float dc = df * c2 + di * g2 + i2 * dg;
                    c2 = f2 * c2 + i2 * g2;
                    float th = tanhf_fast(c2);
                    hs[r] = o2 * th;
                    float dh2 = dd * th + o2 * (1.f - th * th) * dc;
                    float pp = wout * dh2;
#pragma unroll
                    for (int s = 32; s > 0; s >>= 1) pp += __shfl_down(pp, s, 64);
                    if ((r & 63) == 0) red[r >> 6] = pp;
                }
                __syncthreads();
                if (r == 0) gb[c * CH + tl] = red[0] + red[1];
                // red next written after next step's staging barrier — no race
            }
            if (r == 0)
                __hip_atomic_store(cntC, (c + 1) * CH, __ATOMIC_RELEASE, __HIP_MEMORY_SCOPE_AGENT);
        }
    }
}

// ---------------------------------------------------------------------------
// fill: out[b,t,i,j] = (i==j) ? g[b,t] : 0  over the full 4 MB output.
// ---------------------------------------------------------------------------
__global__ void fill_kernel(const float* __restrict__ gbuf,
                            float4* __restrict__ out4) {
    int id   = blockIdx.x * 256 + threadIdx.x;  // 0 .. 262143
    int base = id * 4;
    int j0   = base & 31;
    int i    = (base >> 5) & 31;
    int bt   = base >> 10;                      // 0 .. 1023
    float g  = gbuf[bt];
    float4 v;
    v.x = (j0     == i) ? g : 0.f;
    v.y = (j0 + 1 == i) ? g : 0.f;
    v.z = (j0 + 2 == i) ? g : 0.f;
    v.w = (j0 + 3 == i) ? g : 0.f;
    out4[id] = v;
}

extern "C" void kernel_launch(void* const* d_in, const int* in_sizes, int n_in,
                              void* d_out, int out_size, void* d_ws, size_t ws_size,
                              hipStream_t stream) {
    const float* x     = (const float*)d_in[0];
    const float* w_ih0 = (const float*)d_in[1];
    const float* w_hh0 = (const float*)d_in[2];
    const float* b_ih0 = (const float*)d_in[3];
    const float* b_hh0 = (const float*)d_in[4];
    const float* w_ih1 = (const float*)d_in[5];
    const float* w_hh1 = (const float*)d_in[6];
    const float* b_ih1 = (const float*)d_in[7];
    const float* b_hh1 = (const float*)d_in[8];
    const float* w_out = (const float*)d_in[9];
    // d_in[10] = b_out: constant offset, zero derivative -> unused

    float* ws = (float*)d_ws;   // ~2.1 MB used; 0xAA poison reads as negative ints

    lstm4_kernel<<<dim3(32), dim3(512), 0, stream>>>(x, w_ih0, w_hh0, b_ih0, b_hh0,
                                                     w_ih1, w_hh1, b_ih1, b_hh1, w_out,
                                                     ws);
    fill_kernel<<<dim3(1024), dim3(256), 0, stream>>>(ws + OFF_GBUF, (float4*)d_out);
}

// Round 6
// 284.286 us; speedup vs baseline: 1.2767x; 1.2767x over previous
//
#include <hip/hip_runtime.h>
#include <math.h>

#define H    128
#define TT   128
#define CH   8            // steps per chunk/flag
#define NCH  (TT / CH)    // 16
#define RD   4            // partials ring depth (chunks)

// ws float offsets
#define OFF_H1V   0                 // [b][t][256]           : 262144 floats
#define OFF_P1    262144            // [b][RD][CH][512]      : 131072 floats
#define OFF_P2    393216            // [b][RD][CH][512]      : 131072 floats
#define OFF_CNT   524288            // int counters (1024 reserved)
#define OFF_GBUF  525312            // [b][t]                : 1024 floats

__device__ __forceinline__ float sigf(float x)       { return 1.0f / (1.0f + __expf(-x)); }
__device__ __forceinline__ float tanhf_fast(float x) { return 1.0f - 2.0f / (1.0f + __expf(2.0f * x)); }

// sum over the 4-lane p-group via DPP quad_perm (VALU, no LDS traffic)
__device__ __forceinline__ float quad_sum(float v) {
    int t = __builtin_amdgcn_update_dpp(0, __float_as_int(v), 0xB1, 0xF, 0xF, true); // xor 1
    v += __int_as_float(t);
    t = __builtin_amdgcn_update_dpp(0, __float_as_int(v), 0x4E, 0xF, 0xF, true);     // xor 2
    v += __int_as_float(t);
    return v;
}

// Load one float4 of weights, pin scalars in the register file (no remat loads).
#define DECLW4(nm, src) \
    float4 _t_##nm = (src); \
    float nm##_x = _t_##nm.x, nm##_y = _t_##nm.y, nm##_z = _t_##nm.z, nm##_w = _t_##nm.w; \
    asm volatile("" : "+v"(nm##_x), "+v"(nm##_y), "+v"(nm##_z), "+v"(nm##_w));

// Gate-aligned weight residency: thread (rg,p) holds rows {rg,rg+128,rg+256,rg+384},
// k-slice [32p, 32p+32) -> 128 floats/thread.
#define LOADW_ALL(W) \
    const float4* wpa_ = (const float4*)((W) + (size_t)(rg)       * H + p * 32); \
    const float4* wpb_ = (const float4*)((W) + (size_t)(rg + 128) * H + p * 32); \
    const float4* wpc_ = (const float4*)((W) + (size_t)(rg + 256) * H + p * 32); \
    const float4* wpd_ = (const float4*)((W) + (size_t)(rg + 384) * H + p * 32); \
    DECLW4(wa0, wpa_[0]) DECLW4(wa1, wpa_[1]) DECLW4(wa2, wpa_[2]) DECLW4(wa3, wpa_[3]) \
    DECLW4(wa4, wpa_[4]) DECLW4(wa5, wpa_[5]) DECLW4(wa6, wpa_[6]) DECLW4(wa7, wpa_[7]) \
    DECLW4(wb0, wpb_[0]) DECLW4(wb1, wpb_[1]) DECLW4(wb2, wpb_[2]) DECLW4(wb3, wpb_[3]) \
    DECLW4(wb4, wpb_[4]) DECLW4(wb5, wpb_[5]) DECLW4(wb6, wpb_[6]) DECLW4(wb7, wpb_[7]) \
    DECLW4(wc0, wpc_[0]) DECLW4(wc1, wpc_[1]) DECLW4(wc2, wpc_[2]) DECLW4(wc3, wpc_[3]) \
    DECLW4(wc4, wpc_[4]) DECLW4(wc5, wpc_[5]) DECLW4(wc6, wpc_[6]) DECLW4(wc7, wpc_[7]) \
    DECLW4(wd0, wpd_[0]) DECLW4(wd1, wpd_[1]) DECLW4(wd2, wpd_[2]) DECLW4(wd3, wpd_[3]) \
    DECLW4(wd4, wpd_[4]) DECLW4(wd5, wpd_[5]) DECLW4(wd6, wpd_[6]) DECLW4(wd7, wpd_[7])

#define FMA1(nm, ov, acc) \
    acc = fmaf(nm##_x, ov.x, acc); acc = fmaf(nm##_y, ov.y, acc); \
    acc = fmaf(nm##_z, ov.z, acc); acc = fmaf(nm##_w, ov.w, acc);

#define DOTJ(j) FMA1(wa##j, hv##j, a0) FMA1(wb##j, hv##j, a1) FMA1(wc##j, hv##j, a2) FMA1(wd##j, hv##j, a3)

// 8 b128 broadcast reads + 128 FMA + quad reduction -> a0..a3 = full gate dots
#define DOT_BODY(HBASE) \
    const float4* _hp4 = (const float4*)(HBASE); \
    float4 hv0=_hp4[0],hv1=_hp4[1],hv2=_hp4[2],hv3=_hp4[3], \
           hv4=_hp4[4],hv5=_hp4[5],hv6=_hp4[6],hv7=_hp4[7]; \
    float a0=0.f,a1=0.f,a2=0.f,a3=0.f; \
    DOTJ(0) DOTJ(1) DOTJ(2) DOTJ(3) DOTJ(4) DOTJ(5) DOTJ(6) DOTJ(7) \
    a0 = quad_sum(a0); a1 = quad_sum(a1); a2 = quad_sum(a2); a3 = quad_sum(a3);

#define WAITGE(ptr, val) \
    while (__hip_atomic_load(ptr, __ATOMIC_ACQUIRE, __HIP_MEMORY_SCOPE_AGENT) < (val)) \
        __builtin_amdgcn_s_sleep(1);

// ---------------------------------------------------------------------------
// 4-stage per-batch CU pipeline (32 blocks):
//   role 0 = A : layer-1 recurrence (w_hh0)        -> h1[t], v[t]
//   role 1 = B1: w_ih1 @ h1                        -> part1
//   role 2 = B2: w_ih1 @ v                         -> part2
//   role 3 = C : w_hh1 @ h2 + elementwise + output -> gbuf
// Thread map everywhere: r = rg*4+p; gate-aligned rows, k-slice p.
// h vectors live in LDS as 4 padded slices (stride 36 floats) -> conflict-free.
// ---------------------------------------------------------------------------
__global__ __launch_bounds__(512, 1)
void lstm5_kernel(const float* __restrict__ x,
                  const float* __restrict__ w_ih0,
                  const float* __restrict__ w_hh0,
                  const float* __restrict__ b_ih0,
                  const float* __restrict__ b_hh0,
                  const float* __restrict__ w_ih1,
                  const float* __restrict__ w_hh1,
                  const float* __restrict__ b_ih1,
                  const float* __restrict__ b_hh1,
                  const float* __restrict__ w_out,
                  float* __restrict__ ws) {
    const int role = blockIdx.x >> 3;
    const int b    = blockIdx.x & 7;
    const int r    = threadIdx.x;
    const int rg   = r >> 2;          // h-index 0..127
    const int p    = r & 3;           // k-slice 0..3

    int* cntA  = (int*)ws + OFF_CNT       + b * 16;
    int* cntB1 = (int*)ws + OFF_CNT + 128 + b * 16;
    int* cntB2 = (int*)ws + OFF_CNT + 256 + b * 16;
    int* cntC  = (int*)ws + OFF_CNT + 384 + b * 16;
    float* h1v = ws + OFF_H1V + (size_t)b * TT * 256;

    __shared__ float hbuf[2][144];    // state vector, 4 slices x 36 (A: h1, C: h2)
    __shared__ float u_s[TT];         // A
    __shared__ float scr[512];        // A trace scratch
    __shared__ float hb[CH * 144];    // B chunk staging (padded slices)
    __shared__ float redc[2][8];      // C per-wave partial sums

    const int wsl  = rg >> 5;         // slice owning h[rg]
    const int wpos = rg & 31;

    if (role == 0) {
        // ===================== Stage A: layer-1 recurrence =====================
        LOADW_ALL(w_hh0)
        const float b0 = b_ih0[rg]       + b_hh0[rg];
        const float b1 = b_ih0[rg + 128] + b_hh0[rg + 128];
        const float b2 = b_ih0[rg + 256] + b_hh0[rg + 256];
        const float b3 = b_ih0[rg + 384] + b_hh0[rg + 384];
        const float wi0 = w_ih0[rg], wi1 = w_ih0[rg + 128];
        const float wi2 = w_ih0[rg + 256], wi3 = w_ih0[rg + 384];
        {   // u[t] = trace(x[b,t]) cooperatively (4 partials per t)
            const float* xb = x + (size_t)(b * TT + (r & 127)) * 1024;
            const int pq = r >> 7;
            float u = 0.f;
#pragma unroll
            for (int i = 0; i < 8; i++) u += xb[(pq * 8 + i) * 33];
            scr[r] = u;
        }
        if (r < 144) hbuf[0][r] = 0.f;
        __syncthreads();
        if (r < TT) u_s[r] = scr[r] + scr[r + 128] + scr[r + 256] + scr[r + 384];
        __syncthreads();

        float c1 = 0.f;
        for (int t = 0; t < TT; t++) {
            const float* hc = hbuf[t & 1];
            float* hx = hbuf[(t & 1) ^ 1];
            DOT_BODY(hc + p * 36)
            const float u = u_s[t];
            float z0 = a0 + fmaf(wi0, u, b0);
            float z1 = a1 + fmaf(wi1, u, b1);
            float z2 = a2 + fmaf(wi2, u, b2);
            float z3 = a3 + fmaf(wi3, u, b3);
            float gi = sigf(z0), gf = sigf(z1), gg = tanhf_fast(z2), go = sigf(z3);
            float di = gi * (1.f - gi) * wi0, df = gf * (1.f - gf) * wi1;
            float dg = (1.f - gg * gg) * wi2, dd = go * (1.f - go) * wi3;
            float dc = df * c1 + di * gg + gi * dg;
            c1 = gf * c1 + gi * gg;
            float th = tanhf_fast(c1);
            float hn = go * th;
            float vn = dd * th + go * (1.f - th * th) * dc;
            if (p == wsl) hx[p * 36 + wpos] = hn;          // one writer per h-index
            if (p == 0) h1v[t * 256 + rg] = hn;            // publish for B1
            if (p == 1) h1v[t * 256 + 128 + rg] = vn;      // publish for B2
            __syncthreads();
            if ((t & (CH - 1)) == CH - 1) {
                __threadfence();
                if (r == 0)
                    __hip_atomic_store(cntA, t + 1, __ATOMIC_RELEASE, __HIP_MEMORY_SCOPE_AGENT);
            }
        }
    } else if (role == 1 || role == 2) {
        // ============ Stages B1/B2: w_ih1 @ (h1 | v), chunk-parallel ============
        LOADW_ALL(w_ih1)
        int* myCnt   = (role == 2) ? cntB2 : cntB1;
        float* pbase = ws + ((role == 2) ? OFF_P2 : OFF_P1) + (size_t)b * RD * CH * 512;
        const float* hsrc = h1v + ((role == 2) ? 128 : 0);
        for (int c = 0; c < NCH; c++) {
            if (r == 0) {
                WAITGE(cntA, (c + 1) * CH)
                if (c >= RD) WAITGE(cntC, (c - (RD - 1)) * CH)   // ring backpressure
            }
            __syncthreads();
            if (r < 256) {   // stage chunk into padded slices
                int tl = r >> 5, k4 = r & 31, s = k4 >> 3, j = k4 & 7;
                float4 v = *(const float4*)(hsrc + (size_t)(c * CH + tl) * 256 + k4 * 4);
                *(float4*)&hb[(tl * 4 + s) * 36 + j * 4] = v;
            }
            __syncthreads();
            float* pslot = pbase + (c & (RD - 1)) * CH * 512;
            for (int tl = 0; tl < CH; tl++) {
                DOT_BODY(hb + (tl * 4 + p) * 36)
                // lane p stores gate-p's dot -> pslot[tl][rg*4+p]: fully coalesced,
                // and C reads rows {g*128+rg} back as ONE float4.
                float sel = (p == 0) ? a0 : (p == 1) ? a1 : (p == 2) ? a2 : a3;
                pslot[tl * 512 + r] = sel;
            }
            __threadfence();
            __syncthreads();
            if (r == 0)
                __hip_atomic_store(myCnt, (c + 1) * CH, __ATOMIC_RELEASE, __HIP_MEMORY_SCOPE_AGENT);
        }
    } else {
        // ========= Stage C: w_hh1 @ h2 + layer-2 elementwise + output =========
        LOADW_ALL(w_hh1)
        const float b0 = b_ih1[rg]       + b_hh1[rg];
        const float b1 = b_ih1[rg + 128] + b_hh1[rg + 128];
        const float b2 = b_ih1[rg + 256] + b_hh1[rg + 256];
        const float b3 = b_ih1[rg + 384] + b_hh1[rg + 384];
        const float wo = w_out[rg];
        if (r < 144) hbuf[0][r] = 0.f;
        __syncthreads();
        float c2 = 0.f;
        float* gb = ws + OFF_GBUF + (size_t)b * TT;
        const float* p1b = ws + OFF_P1 + (size_t)b * RD * CH * 512;
        const float* p2b = ws + OFF_P2 + (size_t)b * RD * CH * 512;
        for (int c = 0; c < NCH; c++) {
            if (r == 0) { WAITGE(cntB1, (c + 1) * CH) WAITGE(cntB2, (c + 1) * CH) }
            __syncthreads();
            const float* s1p = p1b + (c & (RD - 1)) * CH * 512;
            const float* s2p = p2b + (c & (RD - 1)) * CH * 512;
            for (int tl = 0; tl < CH; tl++) {
                const int t = c * CH + tl;
                float4 zf = *(const float4*)(s1p + tl * 512 + rg * 4);  // early issue
                float4 af = *(const float4*)(s2p + tl * 512 + rg * 4);
                const float* hc = hbuf[t & 1];
                float* hx = hbuf[(t & 1) ^ 1];
                DOT_BODY(hc + p * 36)
                float z0 = a0 + b0 + zf.x;
                float z1 = a1 + b1 + zf.y;
                float z2 = a2 + b2 + zf.z;
                float z3 = a3 + b3 + zf.w;
                float gi = sigf(z0), gf = sigf(z1), gg = tanhf_fast(z2), go = sigf(z3);
                float di = gi * (1.f - gi) * af.x, df = gf * (1.f - gf) * af.y;
                float dg = (1.f - gg * gg) * af.z, dd = go * (1.f - go) * af.w;
                float dc = df * c2 + di * gg + gi * dg;
                c2 = gf * c2 + gi * gg;
                float th = tanhf_fast(c2);
                if (p == wsl) hx[p * 36 + wpos] = go * th;
                float dh2 = dd * th + go * (1.f - th * th) * dc;
                float pv = (p == 0) ? wo * dh2 : 0.f;   // one contribution per rg
#pragma unroll
                for (int s = 32; s > 0; s >>= 1) pv += __shfl_xor(pv, s, 64);
                if ((r & 63) == 0) redc[t & 1][r >> 6] = pv;
                __syncthreads();
                if (r == 0) {
                    float g = 0.f;
#pragma unroll
                    for (int w = 0; w < 8; w++) g += redc[t & 1][w];
                    gb[t] = g;
                }
            }
            if (r == 0)
                __hip_atomic_store(cntC, (c + 1) * CH, __ATOMIC_RELEASE, __HIP_MEMORY_SCOPE_AGENT);
        }
    }
}

// ---------------------------------------------------------------------------
// fill: out[b,t,i,j] = (i==j) ? g[b,t] : 0  over the full 4 MB output.
// ---------------------------------------------------------------------------
__global__ void fill_kernel(const float* __restrict__ gbuf,
                            float4* __restrict__ out4) {
    int id   = blockIdx.x * 256 + threadIdx.x;  // 0 .. 262143
    int base = id * 4;
    int j0   = base & 31;
    int i    = (base >> 5) & 31;
    int bt   = base >> 10;                      // 0 .. 1023
    float g  = gbuf[bt];
    float4 v;
    v.x = (j0     == i) ? g : 0.f;
    v.y = (j0 + 1 == i) ? g : 0.f;
    v.z = (j0 + 2 == i) ? g : 0.f;
    v.w = (j0 + 3 == i) ? g : 0.f;
    out4[id] = v;
}

extern "C" void kernel_launch(void* const* d_in, const int* in_sizes, int n_in,
                              void* d_out, int out_size, void* d_ws, size_t ws_size,
                              hipStream_t stream) {
    const float* x     = (const float*)d_in[0];
    const float* w_ih0 = (const float*)d_in[1];
    const float* w_hh0 = (const float*)d_in[2];
    const float* b_ih0 = (const float*)d_in[3];
    const float* b_hh0 = (const float*)d_in[4];
    const float* w_ih1 = (const float*)d_in[5];
    const float* w_hh1 = (const float*)d_in[6];
    const float* b_ih1 = (const float*)d_in[7];
    const float* b_hh1 = (const float*)d_in[8];
    const float* w_out = (const float*)d_in[9];
    // d_in[10] = b_out: constant offset, zero derivative -> unused

    float* ws = (float*)d_ws;   // ~2.1 MB used; 0xAA poison reads as negative ints

    lstm5_kernel<<<dim3(32), dim3(512), 0, stream>>>(x, w_ih0, w_hh0, b_ih0, b_hh0,
                                                     w_ih1, w_hh1, b_ih1, b_hh1, w_out,
                                                     ws);
    fill_kernel<<<dim3(1024), dim3(256), 0, stream>>>(ws + OFF_GBUF, (float4*)d_out);
}